// Round 5
// baseline (438.964 us; speedup 1.0000x reference)
//
#include <hip/hip_runtime.h>

#define BB 2
#define NN 2048
#define HH 16
#define MODEL 1024
#define CSC 0.18033688011112042f  // 0.125 * log2(e)

typedef short bf16x8 __attribute__((ext_vector_type(8)));
typedef float f32x4 __attribute__((ext_vector_type(4)));
typedef int i32x2 __attribute__((ext_vector_type(2)));

__device__ __forceinline__ unsigned short f2bf(float x) {
  unsigned int u = __builtin_bit_cast(unsigned int, x);
  u += 0x7fffu + ((u >> 16) & 1u);
  return (unsigned short)(u >> 16);
}

__device__ __forceinline__ unsigned int pack_bf2(float a, float b) {
  unsigned int ua = __builtin_bit_cast(unsigned int, a) + 0x8000u;
  unsigned int ub = __builtin_bit_cast(unsigned int, b) + 0x8000u;
  return __builtin_amdgcn_perm(ub, ua, 0x07060302u);  // lo16=bf(a), hi16=bf(b)
}

// RNE pack (matches prep's f2bf exactly): lo16=bf(a), hi16=bf(b)
__device__ __forceinline__ unsigned int pack2_rne(float a, float b) {
  return (unsigned int)f2bf(a) | ((unsigned int)f2bf(b) << 16);
}

__device__ __forceinline__ float fast_exp2(float x) {
#if __has_builtin(__builtin_amdgcn_exp2f)
  return __builtin_amdgcn_exp2f(x);
#else
  return exp2f(x);
#endif
}

__device__ __forceinline__ f32x4 mfma16(bf16x8 a, bf16x8 b, f32x4 c) {
  return __builtin_amdgcn_mfma_f32_16x16x32_bf16(a, b, c, 0, 0, 0);
}

__device__ __forceinline__ void async_copy16(void* lds_base, const void* g) {
  __builtin_amdgcn_global_load_lds(
      (const __attribute__((address_space(1))) void*)g,
      (__attribute__((address_space(3))) void*)lds_base, 16, 0, 0);
}

// Prep v2: q section REMOVED (flash reads q fp32 directly). k/w cvt + V
// transpose + bias table. biasTab entries carry the fixed shift: bias*CSC-12.
__global__ void prep_kernel(const float* __restrict__ k, const float* __restrict__ w,
                            const float* __restrict__ v, const float* __restrict__ rel_emb,
                            unsigned short* __restrict__ kb, unsigned short* __restrict__ wb,
                            unsigned short* __restrict__ vt, float* __restrict__ biasTab) {
  __shared__ unsigned short tile[64][65];
  const int NK4 = BB * NN * MODEL / 4;  // 1048576 float4s of k
  const int blk = blockIdx.x;
  if (blk < 5120) {  // k (4096 blocks) + w (1024 blocks)
    int i = blk * 256 + threadIdx.x;
    const float* src;
    unsigned short* dst;
    int j = i;
    if (i < NK4) {
      src = k; dst = kb;
    } else {
      src = w; dst = wb; j = i - NK4;
    }
    float4 f = reinterpret_cast<const float4*>(src)[j];
    ushort4 u;
    u.x = f2bf(f.x); u.y = f2bf(f.y); u.z = f2bf(f.z); u.w = f2bf(f.w);
    reinterpret_cast<ushort4*>(dst)[j] = u;
  } else if (blk < 6144) {  // vt[b][h][d][n] = bf16(v[b][n][h*64+d])
    const int blk2 = blk - 5120;
    const int n0 = (blk2 & 31) * 64;
    const int bh = blk2 >> 5;
    const int b = bh >> 4, h = bh & 15;
    const int c = threadIdx.x & 63;
    const int r = threadIdx.x >> 6;
#pragma unroll
    for (int i = 0; i < 16; ++i) {
      int nl = r * 16 + i;
      tile[c][nl] = f2bf(v[((long)(b * NN + n0 + nl)) * MODEL + h * 64 + c]);
    }
    __syncthreads();
#pragma unroll
    for (int i = 0; i < 16; ++i) {
      int d = r * 16 + i;
      vt[((long)(bh * 64 + d)) * NN + n0 + c] = tile[d][c];
    }
  } else {  // biasTab[h][rel+2047] = bias(rel)*CSC - 12 (log2 domain + fixed shift)
    int idx = (blk - 6144) * 256 + threadIdx.x;
    if (idx >= 4095) return;
    int rel = idx - 2047;
    int nn = rel < 0 ? -rel : rel;
    int bucket;
    if (nn < 8) {
      bucket = nn;
    } else {
      float val = logf((float)nn * 0.125f) / logf(16.0f) * 8.0f;
      int vl = 8 + (int)val;
      if (vl > 15) vl = 15;
      bucket = vl;
    }
    if (rel >= 0) bucket += 16;
#pragma unroll
    for (int h = 0; h < 16; ++h)
      biasTab[h * 4095 + idx] = rel_emb[bucket * 16 + h] * CSC - 12.0f;
  }
}

// Flash v12 = flash10 numerics (f2bf/pack_bf2 — bit-identical to the passing
// round-3 kernel; the round-4 cvt_pk_bf16 substitution is the isolated
// failure cause and is reverted) + the value-neutral structural wins:
//  - q fp32 direct read + in-register RNE convert (kills prep's q section)
//  - K register double-buffer ping-pong: prefetch K(it+1) under body(it)
//    compute. Budget: 128 VGPR + 64 AGPR + 32 prefetch ~= 224 <= 256 @2w/SIMD.
//  - s_setprio(1) around MFMA clusters (staggered-wave regime).
__global__ __launch_bounds__(256, 2) void flash12(
    const float* __restrict__ qf32, const unsigned short* __restrict__ kb,
    const unsigned short* __restrict__ vtb, const float* __restrict__ biasTab,
    unsigned short* __restrict__ attn) {
  // obuf: post-loop O^T merge [4][64][68] + l partials in the 4-slot row pad.
  __shared__ __align__(16) float obuf[4 * 64 * 68];  // 69632 B
  __shared__ __align__(16) float scratch[512];       // bias span

  // XCD swizzle: all 32 q-tiles of one bh on one XCD (K/V L2-resident)
  const int i = blockIdx.x;
  const int bh = (i & 7) * 4 + ((i >> 3) >> 5);
  const int qt = (i >> 3) & 31;
  const int b = bh >> 4, h = bh & 15;
  const int q0 = qt * 64;
  const int tid = threadIdx.x, w = tid >> 6, lane = tid & 63;
  const int g = lane >> 4, c = lane & 15;

  const float* btab = biasTab + h * 4095 + 2047;
  for (int j = tid; j < 441; j += 256) scratch[j] = btab[j - 220];
  const float cPos = btab[200], cNeg = btab[-200];  // saturated buckets (|rel|>=91)
  __syncthreads();

  // Q B-frags for all 64 q-rows, converted fp32->bf16 in-register (one-time,
  // RNE — identical values to the old prep qb path)
  bf16x8 qf0[4], qf1[4];
  const float* qbase = qf32 + ((long)(b * NN + q0)) * MODEL + h * 64;
#pragma unroll
  for (int nt = 0; nt < 4; ++nt) {
    const float* r = qbase + (16 * nt + c) * MODEL + 8 * g;
    float4 f0 = *reinterpret_cast<const float4*>(r);
    float4 f1 = *reinterpret_cast<const float4*>(r + 4);
    float4 f2 = *reinterpret_cast<const float4*>(r + 32);
    float4 f3 = *reinterpret_cast<const float4*>(r + 36);
    qf0[nt] = __builtin_bit_cast(bf16x8, uint4{pack2_rne(f0.x, f0.y), pack2_rne(f0.z, f0.w),
                                               pack2_rne(f1.x, f1.y), pack2_rne(f1.z, f1.w)});
    qf1[nt] = __builtin_bit_cast(bf16x8, uint4{pack2_rne(f2.x, f2.y), pack2_rne(f2.z, f2.w),
                                               pack2_rne(f3.x, f3.y), pack2_rne(f3.z, f3.w)});
  }

  const unsigned short* kbase = kb + ((long)b * NN) * MODEL + h * 64;
  const unsigned short* vbase = vtb + ((long)bh * 64) * NN;

  f32x4 o[4][4];
  float l_p[4] = {0.f, 0.f, 0.f, 0.f};  // per-lane partial sums
#pragma unroll
  for (int mt = 0; mt < 4; ++mt)
#pragma unroll
    for (int nt = 0; nt < 4; ++nt) o[mt][nt] = f32x4{0.f, 0.f, 0.f, 0.f};

  auto loadK = [&](int kt, bf16x8 (&K0)[4], bf16x8 (&K1)[4]) {
    const unsigned short* krow = kbase + (long)(kt * 64) * MODEL;
#pragma unroll
    for (int mt = 0; mt < 4; ++mt) {
      const unsigned short* r = krow + (16 * mt + c) * MODEL + 8 * g;
      K0[mt] = *reinterpret_cast<const bf16x8*>(r);
      K1[mt] = *reinterpret_cast<const bf16x8*>(r + 32);
    }
  };

  auto body = [&](int it, bf16x8 (&K0)[4], bf16x8 (&K1)[4],
                  bf16x8 (&N0)[4], bf16x8 (&N1)[4]) {
    const int kt = w + 4 * it;  // this wave's private key-tile
    bf16x8 vf0[4], vf1[4];
    const unsigned short* vrow = vbase + kt * 64;
#pragma unroll
    for (int mt = 0; mt < 4; ++mt) {
      const unsigned short* r = vrow + (long)(16 * mt + c) * NN + 8 * g;
      vf0[mt] = *reinterpret_cast<const bf16x8*>(r);
      vf1[mt] = *reinterpret_cast<const bf16x8*>(r + 32);
    }
    if (it < 7) loadK(kt + 4, N0, N1);  // prefetch next K into the spare bank

    const int lo = kt * 64 - q0 - 63, hi = kt * 64 + 63 - q0;
    const bool sat = (lo >= 91 || hi <= -91);
    const float cb = (lo >= 91) ? cPos : cNeg;

#pragma unroll
    for (int nt = 0; nt < 4; ++nt) {
      // S^T chain nt: lane (g,c) reg rr = S[qrow=16nt+c][key=16mt+4g+rr]
      f32x4 s[4];
      __builtin_amdgcn_s_setprio(1);
#pragma unroll
      for (int mt = 0; mt < 4; ++mt) {
        s[mt] = mfma16(K0[mt], qf0[nt], f32x4{0.f, 0.f, 0.f, 0.f});
        s[mt] = mfma16(K1[mt], qf1[nt], s[mt]);
      }
      __builtin_amdgcn_s_setprio(0);
      // logits (log2 domain, fixed -12 shift folded into table/consts)
      if (sat) {
#pragma unroll
        for (int mt = 0; mt < 4; ++mt)
#pragma unroll
          for (int rr = 0; rr < 4; ++rr) s[mt][rr] = s[mt][rr] * CSC + cb;
      } else {
        const int base = kt * 64 + 4 * g - q0 - 16 * nt - c + 220;
#pragma unroll
        for (int mt = 0; mt < 4; ++mt)
#pragma unroll
          for (int rr = 0; rr < 4; ++rr)
            s[mt][rr] = s[mt][rr] * CSC + scratch[base + 16 * mt + rr];
      }
      // P = exp2(lg): no max tracking, no shuffles; per-lane partial l
      float sum = 0.f;
      unsigned int pk[4][2];
#pragma unroll
      for (int mt = 0; mt < 4; ++mt) {
        const float p0 = fast_exp2(s[mt][0]);
        const float p1 = fast_exp2(s[mt][1]);
        const float p2 = fast_exp2(s[mt][2]);
        const float p3 = fast_exp2(s[mt][3]);
        sum += (p0 + p1) + (p2 + p3);
        pk[mt][0] = pack_bf2(p0, p1);
        pk[mt][1] = pack_bf2(p2, p3);
      }
      l_p[nt] += sum;
      // T12: in-register C-layout -> B-frag rearrangement (no LDS, no waits).
      unsigned int d0, d1, d2, d3, d4, d5, d6, d7;
      {
        i32x2 x, y;
        x = __builtin_amdgcn_permlane32_swap((int)pk[0][0], (int)pk[1][0], false, false);
        y = __builtin_amdgcn_permlane16_swap(x[0], x[1], false, false);
        d0 = (unsigned int)y[0]; d2 = (unsigned int)y[1];
        x = __builtin_amdgcn_permlane32_swap((int)pk[0][1], (int)pk[1][1], false, false);
        y = __builtin_amdgcn_permlane16_swap(x[0], x[1], false, false);
        d1 = (unsigned int)y[0]; d3 = (unsigned int)y[1];
        x = __builtin_amdgcn_permlane32_swap((int)pk[2][0], (int)pk[3][0], false, false);
        y = __builtin_amdgcn_permlane16_swap(x[0], x[1], false, false);
        d4 = (unsigned int)y[0]; d6 = (unsigned int)y[1];
        x = __builtin_amdgcn_permlane32_swap((int)pk[2][1], (int)pk[3][1], false, false);
        y = __builtin_amdgcn_permlane16_swap(x[0], x[1], false, false);
        d5 = (unsigned int)y[0]; d7 = (unsigned int)y[1];
      }
      const bf16x8 pb0 = __builtin_bit_cast(bf16x8, uint4{d0, d1, d2, d3});
      const bf16x8 pb1 = __builtin_bit_cast(bf16x8, uint4{d4, d5, d6, d7});
      __builtin_amdgcn_s_setprio(1);
#pragma unroll
      for (int mt = 0; mt < 4; ++mt) {
        o[mt][nt] = mfma16(vf0[mt], pb0, o[mt][nt]);  // O^T[d][qrow]
        o[mt][nt] = mfma16(vf1[mt], pb1, o[mt][nt]);
      }
      __builtin_amdgcn_s_setprio(0);
    }
  };

  bf16x8 kA0[4], kA1[4], kB0[4], kB1[4];
  loadK(w, kA0, kA1);
  body(0, kA0, kA1, kB0, kB1);
  body(1, kB0, kB1, kA0, kA1);
  body(2, kA0, kA1, kB0, kB1);
  body(3, kB0, kB1, kA0, kA1);
  body(4, kA0, kA1, kB0, kB1);
  body(5, kB0, kB1, kA0, kA1);
  body(6, kA0, kA1, kB0, kB1);
  body(7, kB0, kB1, kA0, kA1);

  // ---- merge (pure sums — fixed shift means no max weighting) ----
  __syncthreads();
  float* ob = obuf + w * 64 * 68;
#pragma unroll
  for (int nt = 0; nt < 4; ++nt) {
    ob[(16 * nt + c) * 68 + 64 + g] = l_p[nt];
#pragma unroll
    for (int mt = 0; mt < 4; ++mt)
      *reinterpret_cast<f32x4*>(&ob[(16 * nt + c) * 68 + 16 * mt + 4 * g]) = o[mt][nt];
  }
  __syncthreads();

  // wave w owns q-rows 16w..16w+15; lane (g,c) -> qrow 16w+c, dims 8g+j & 32+8g+j
  const int qr = 16 * w + c;
  float l = 0.f;
#pragma unroll
  for (int u = 0; u < 4; ++u)
#pragma unroll
    for (int gg = 0; gg < 4; ++gg) l += obuf[(u * 64 + qr) * 68 + 64 + gg];
  const float inv = 1.f / l;

  float acc[16];
#pragma unroll
  for (int j = 0; j < 16; ++j) acc[j] = 0.f;
#pragma unroll
  for (int u = 0; u < 4; ++u) {
    const float* src = obuf + (u * 64 + qr) * 68;
    f32x4 r0 = *reinterpret_cast<const f32x4*>(&src[8 * g]);
    f32x4 r1 = *reinterpret_cast<const f32x4*>(&src[8 * g + 4]);
    f32x4 r2 = *reinterpret_cast<const f32x4*>(&src[32 + 8 * g]);
    f32x4 r3 = *reinterpret_cast<const f32x4*>(&src[32 + 8 * g + 4]);
#pragma unroll
    for (int j = 0; j < 4; ++j) {
      acc[j] += r0[j];
      acc[4 + j] += r1[j];
      acc[8 + j] += r2[j];
      acc[12 + j] += r3[j];
    }
  }
  unsigned int od[8];
#pragma unroll
  for (int t = 0; t < 8; ++t) od[t] = pack_bf2(acc[2 * t] * inv, acc[2 * t + 1] * inv);
  unsigned short* orow = attn + ((long)(b * NN + q0 + qr)) * MODEL + h * 64;
  *reinterpret_cast<uint4*>(orow + 8 * g) = uint4{od[0], od[1], od[2], od[3]};
  *reinterpret_cast<uint4*>(orow + 32 + 8 * g) = uint4{od[4], od[5], od[6], od[7]};
}

// out[i][j] = sum_k attn[i][k] * w[j][k] + b[j]; tile 128x64, BK=64,
// 8-chunk XOR swizzle. v2: double-buffered LDS + single barrier/tile
// (T3-minimum 2-phase): stage(t+1) issued BEFORE compute(t) so the
// global_load_lds of the next tile overlaps this tile's MFMAs.
__global__ void proj_gemm_kernel(const unsigned short* __restrict__ A,
                                 const unsigned short* __restrict__ Bw,
                                 const float* __restrict__ bias,
                                 float* __restrict__ out) {
  __shared__ __align__(16) unsigned short At[2][128 * 64];
  __shared__ __align__(16) unsigned short Bt[2][64 * 64];
  int bm0 = blockIdx.x * 128, bn0 = blockIdx.y * 64;
  int tid = threadIdx.x, w = tid >> 6, lane = tid & 63;
  int g = lane >> 4, c = lane & 15;
  int m0 = (w & 1) * 64, n0 = (w >> 1) * 32;

  f32x4 acc[4][2];
#pragma unroll
  for (int mi = 0; mi < 4; ++mi)
#pragma unroll
    for (int nj = 0; nj < 2; ++nj) acc[mi][nj] = f32x4{0.f, 0.f, 0.f, 0.f};

  int rloc = lane >> 3, p = lane & 7;

  auto stage = [&](int buf, int kt) {
#pragma unroll
    for (int t = 0; t < 4; ++t) {
      int row = w * 32 + t * 8 + rloc;
      async_copy16(&At[buf][(w * 32 + t * 8) * 64],
                   A + (long)(bm0 + row) * 1024 + kt * 64 + (p ^ rloc) * 8);
    }
#pragma unroll
    for (int t = 0; t < 2; ++t) {
      int row = w * 16 + t * 8 + rloc;
      async_copy16(&Bt[buf][(w * 16 + t * 8) * 64],
                   Bw + (long)(bn0 + row) * 1024 + kt * 64 + (p ^ rloc) * 8);
    }
  };

  int cur = 0;
  stage(0, 0);
  for (int kt = 0; kt < 16; ++kt) {
    __syncthreads();  // drains vmcnt(0): tile kt resident; prev reads done
    if (kt < 15) stage(cur ^ 1, kt + 1);

    bf16x8 af0[4], af1[4], bf0[2], bf1[2];
#pragma unroll
    for (int mi = 0; mi < 4; ++mi) {
      int row = m0 + 16 * mi + c, sw = row & 7;
      af0[mi] = *reinterpret_cast<const bf16x8*>(&At[cur][row * 64 + (g ^ sw) * 8]);
      af1[mi] = *reinterpret_cast<const bf16x8*>(&At[cur][row * 64 + ((4 + g) ^ sw) * 8]);
    }
#pragma unroll
    for (int nj = 0; nj < 2; ++nj) {
      int row = n0 + 16 * nj + c, sw = row & 7;
      bf0[nj] = *reinterpret_cast<const bf16x8*>(&Bt[cur][row * 64 + (g ^ sw) * 8]);
      bf1[nj] = *reinterpret_cast<const bf16x8*>(&Bt[cur][row * 64 + ((4 + g) ^ sw) * 8]);
    }
#pragma unroll
    for (int mi = 0; mi < 4; ++mi)
#pragma unroll
      for (int nj = 0; nj < 2; ++nj) {
        acc[mi][nj] = mfma16(af0[mi], bf0[nj], acc[mi][nj]);
        acc[mi][nj] = mfma16(af1[mi], bf1[nj], acc[mi][nj]);
      }
    cur ^= 1;
  }

#pragma unroll
  for (int mi = 0; mi < 4; ++mi)
#pragma unroll
    for (int nj = 0; nj < 2; ++nj)
#pragma unroll
      for (int r = 0; r < 4; ++r) {
        int row = bm0 + m0 + mi * 16 + 4 * g + r;
        int col = bn0 + n0 + nj * 16 + c;
        out[(long)row * 1024 + col] = acc[mi][nj][r] + bias[col];
      }
}

extern "C" void kernel_launch(void* const* d_in, const int* in_sizes, int n_in,
                              void* d_out, int out_size, void* d_ws, size_t ws_size,
                              hipStream_t stream) {
  const float* q = (const float*)d_in[0];
  const float* k = (const float*)d_in[1];
  const float* v = (const float*)d_in[2];
  const float* rel_emb = (const float*)d_in[3];
  const float* w_out = (const float*)d_in[4];
  const float* b_out = (const float*)d_in[5];
  float* out = (float*)d_out;

  char* ws = (char*)d_ws;
  unsigned short* kb   = (unsigned short*)(ws + (8u << 20));
  unsigned short* vt   = (unsigned short*)(ws + (16u << 20));
  unsigned short* attn = (unsigned short*)(ws + (24u << 20));
  unsigned short* wb   = (unsigned short*)(ws + (32u << 20));
  float* biasTab       = (float*)(ws + (34u << 20));

  hipLaunchKernelGGL(prep_kernel, dim3(6161), dim3(256), 0, stream,
                     k, w_out, v, rel_emb, kb, wb, vt, biasTab);
  hipLaunchKernelGGL(flash12, dim3(1024), dim3(256), 0, stream,
                     q, kb, vt, biasTab, attn);
  hipLaunchKernelGGL(proj_gemm_kernel, dim3(32, 16), dim3(256), 0, stream,
                     attn, wb, b_out, out);
}

// Round 6
// 185.301 us; speedup vs baseline: 2.3689x; 2.3689x over previous
//
#include <hip/hip_runtime.h>

#define BB 2
#define NN 2048
#define HH 16
#define MODEL 1024
#define CSC 0.18033688011112042f  // 0.125 * log2(e)

typedef short bf16x8 __attribute__((ext_vector_type(8)));
typedef float f32x4 __attribute__((ext_vector_type(4)));
typedef int i32x2 __attribute__((ext_vector_type(2)));

__device__ __forceinline__ unsigned short f2bf(float x) {
  unsigned int u = __builtin_bit_cast(unsigned int, x);
  u += 0x7fffu + ((u >> 16) & 1u);
  return (unsigned short)(u >> 16);
}

__device__ __forceinline__ unsigned int pack_bf2(float a, float b) {
  unsigned int ua = __builtin_bit_cast(unsigned int, a) + 0x8000u;
  unsigned int ub = __builtin_bit_cast(unsigned int, b) + 0x8000u;
  return __builtin_amdgcn_perm(ub, ua, 0x07060302u);  // lo16=bf(a), hi16=bf(b)
}

// RNE pack (matches prep's f2bf exactly): lo16=bf(a), hi16=bf(b)
__device__ __forceinline__ unsigned int pack2_rne(float a, float b) {
  return (unsigned int)f2bf(a) | ((unsigned int)f2bf(b) << 16);
}

__device__ __forceinline__ float fast_exp2(float x) {
#if __has_builtin(__builtin_amdgcn_exp2f)
  return __builtin_amdgcn_exp2f(x);
#else
  return exp2f(x);
#endif
}

__device__ __forceinline__ f32x4 mfma16(bf16x8 a, bf16x8 b, f32x4 c) {
  return __builtin_amdgcn_mfma_f32_16x16x32_bf16(a, b, c, 0, 0, 0);
}

__device__ __forceinline__ void async_copy16(void* lds_base, const void* g) {
  __builtin_amdgcn_global_load_lds(
      (const __attribute__((address_space(1))) void*)g,
      (__attribute__((address_space(3))) void*)lds_base, 16, 0, 0);
}

// Prep v2: q section REMOVED (flash reads q fp32 directly). k/w cvt + V
// transpose + bias table. biasTab entries carry the fixed shift: bias*CSC-12.
__global__ void prep_kernel(const float* __restrict__ k, const float* __restrict__ w,
                            const float* __restrict__ v, const float* __restrict__ rel_emb,
                            unsigned short* __restrict__ kb, unsigned short* __restrict__ wb,
                            unsigned short* __restrict__ vt, float* __restrict__ biasTab) {
  __shared__ unsigned short tile[64][65];
  const int NK4 = BB * NN * MODEL / 4;  // 1048576 float4s of k
  const int blk = blockIdx.x;
  if (blk < 5120) {  // k (4096 blocks) + w (1024 blocks)
    int i = blk * 256 + threadIdx.x;
    const float* src;
    unsigned short* dst;
    int j = i;
    if (i < NK4) {
      src = k; dst = kb;
    } else {
      src = w; dst = wb; j = i - NK4;
    }
    float4 f = reinterpret_cast<const float4*>(src)[j];
    ushort4 u;
    u.x = f2bf(f.x); u.y = f2bf(f.y); u.z = f2bf(f.z); u.w = f2bf(f.w);
    reinterpret_cast<ushort4*>(dst)[j] = u;
  } else if (blk < 6144) {  // vt[b][h][d][n] = bf16(v[b][n][h*64+d])
    const int blk2 = blk - 5120;
    const int n0 = (blk2 & 31) * 64;
    const int bh = blk2 >> 5;
    const int b = bh >> 4, h = bh & 15;
    const int c = threadIdx.x & 63;
    const int r = threadIdx.x >> 6;
#pragma unroll
    for (int i = 0; i < 16; ++i) {
      int nl = r * 16 + i;
      tile[c][nl] = f2bf(v[((long)(b * NN + n0 + nl)) * MODEL + h * 64 + c]);
    }
    __syncthreads();
#pragma unroll
    for (int i = 0; i < 16; ++i) {
      int d = r * 16 + i;
      vt[((long)(bh * 64 + d)) * NN + n0 + c] = tile[d][c];
    }
  } else {  // biasTab[h][rel+2047] = bias(rel)*CSC - 12 (log2 domain + fixed shift)
    int idx = (blk - 6144) * 256 + threadIdx.x;
    if (idx >= 4095) return;
    int rel = idx - 2047;
    int nn = rel < 0 ? -rel : rel;
    int bucket;
    if (nn < 8) {
      bucket = nn;
    } else {
      float val = logf((float)nn * 0.125f) / logf(16.0f) * 8.0f;
      int vl = 8 + (int)val;
      if (vl > 15) vl = 15;
      bucket = vl;
    }
    if (rel >= 0) bucket += 16;
#pragma unroll
    for (int h = 0; h < 16; ++h)
      biasTab[h * 4095 + idx] = rel_emb[bucket * 16 + h] * CSC - 12.0f;
  }
}

// Flash v13 = flash10's exact loop structure (K/V loaded per-iteration, NO
// register ping-pong — rounds 4&5 proved K-prefetch spills: the live-set
// ceiling at 2 waves/SIMD is ~200 regs incl. transients and flash10 already
// sits there) + the two register-neutral wins from round 5:
//  - q fp32 direct read + in-register RNE convert (kills prep's q section)
//  - s_setprio(1) around MFMA clusters (staggered-wave regime, zero regs)
// Numerics: f2bf/pack_bf2 everywhere — bit-identical to passing rounds 3/5.
__global__ __launch_bounds__(256, 2) void flash13(
    const float* __restrict__ qf32, const unsigned short* __restrict__ kb,
    const unsigned short* __restrict__ vtb, const float* __restrict__ biasTab,
    unsigned short* __restrict__ attn) {
  // obuf: post-loop O^T merge [4][64][68] + l partials in the 4-slot row pad.
  __shared__ __align__(16) float obuf[4 * 64 * 68];  // 69632 B
  __shared__ __align__(16) float scratch[512];       // bias span

  // XCD swizzle: all 32 q-tiles of one bh on one XCD (K/V L2-resident)
  const int i = blockIdx.x;
  const int bh = (i & 7) * 4 + ((i >> 3) >> 5);
  const int qt = (i >> 3) & 31;
  const int b = bh >> 4, h = bh & 15;
  const int q0 = qt * 64;
  const int tid = threadIdx.x, w = tid >> 6, lane = tid & 63;
  const int g = lane >> 4, c = lane & 15;

  const float* btab = biasTab + h * 4095 + 2047;
  for (int j = tid; j < 441; j += 256) scratch[j] = btab[j - 220];
  const float cPos = btab[200], cNeg = btab[-200];  // saturated buckets (|rel|>=91)
  __syncthreads();

  // Q B-frags for all 64 q-rows, converted fp32->bf16 in-register (one-time,
  // RNE — identical values to the old prep qb path)
  bf16x8 qf0[4], qf1[4];
  const float* qbase = qf32 + ((long)(b * NN + q0)) * MODEL + h * 64;
#pragma unroll
  for (int nt = 0; nt < 4; ++nt) {
    const float* r = qbase + (16 * nt + c) * MODEL + 8 * g;
    float4 f0 = *reinterpret_cast<const float4*>(r);
    float4 f1 = *reinterpret_cast<const float4*>(r + 4);
    float4 f2 = *reinterpret_cast<const float4*>(r + 32);
    float4 f3 = *reinterpret_cast<const float4*>(r + 36);
    qf0[nt] = __builtin_bit_cast(bf16x8, uint4{pack2_rne(f0.x, f0.y), pack2_rne(f0.z, f0.w),
                                               pack2_rne(f1.x, f1.y), pack2_rne(f1.z, f1.w)});
    qf1[nt] = __builtin_bit_cast(bf16x8, uint4{pack2_rne(f2.x, f2.y), pack2_rne(f2.z, f2.w),
                                               pack2_rne(f3.x, f3.y), pack2_rne(f3.z, f3.w)});
  }

  const unsigned short* kbase = kb + ((long)b * NN) * MODEL + h * 64;
  const unsigned short* vbase = vtb + ((long)bh * 64) * NN;

  f32x4 o[4][4];
  float l_p[4] = {0.f, 0.f, 0.f, 0.f};  // per-lane partial sums
#pragma unroll
  for (int mt = 0; mt < 4; ++mt)
#pragma unroll
    for (int nt = 0; nt < 4; ++nt) o[mt][nt] = f32x4{0.f, 0.f, 0.f, 0.f};

  for (int it = 0; it < 8; ++it) {
    const int kt = w + 4 * it;  // this wave's private key-tile
    bf16x8 kf0[4], kf1[4];
    const unsigned short* krow = kbase + (long)(kt * 64) * MODEL;
#pragma unroll
    for (int mt = 0; mt < 4; ++mt) {
      const unsigned short* r = krow + (16 * mt + c) * MODEL + 8 * g;
      kf0[mt] = *reinterpret_cast<const bf16x8*>(r);
      kf1[mt] = *reinterpret_cast<const bf16x8*>(r + 32);
    }
    bf16x8 vf0[4], vf1[4];
    const unsigned short* vrow = vbase + kt * 64;
#pragma unroll
    for (int mt = 0; mt < 4; ++mt) {
      const unsigned short* r = vrow + (long)(16 * mt + c) * NN + 8 * g;
      vf0[mt] = *reinterpret_cast<const bf16x8*>(r);
      vf1[mt] = *reinterpret_cast<const bf16x8*>(r + 32);
    }
    const int lo = kt * 64 - q0 - 63, hi = kt * 64 + 63 - q0;
    const bool sat = (lo >= 91 || hi <= -91);
    const float cb = (lo >= 91) ? cPos : cNeg;

#pragma unroll
    for (int nt = 0; nt < 4; ++nt) {
      // S^T chain nt: lane (g,c) reg rr = S[qrow=16nt+c][key=16mt+4g+rr]
      f32x4 s[4];
      __builtin_amdgcn_s_setprio(1);
#pragma unroll
      for (int mt = 0; mt < 4; ++mt) {
        s[mt] = mfma16(kf0[mt], qf0[nt], f32x4{0.f, 0.f, 0.f, 0.f});
        s[mt] = mfma16(kf1[mt], qf1[nt], s[mt]);
      }
      __builtin_amdgcn_s_setprio(0);
      // logits (log2 domain, fixed -12 shift folded into table/consts)
      if (sat) {
#pragma unroll
        for (int mt = 0; mt < 4; ++mt)
#pragma unroll
          for (int rr = 0; rr < 4; ++rr) s[mt][rr] = s[mt][rr] * CSC + cb;
      } else {
        const int base = kt * 64 + 4 * g - q0 - 16 * nt - c + 220;
#pragma unroll
        for (int mt = 0; mt < 4; ++mt)
#pragma unroll
          for (int rr = 0; rr < 4; ++rr)
            s[mt][rr] = s[mt][rr] * CSC + scratch[base + 16 * mt + rr];
      }
      // P = exp2(lg): no max tracking, no shuffles; per-lane partial l
      float sum = 0.f;
      unsigned int pk[4][2];
#pragma unroll
      for (int mt = 0; mt < 4; ++mt) {
        const float p0 = fast_exp2(s[mt][0]);
        const float p1 = fast_exp2(s[mt][1]);
        const float p2 = fast_exp2(s[mt][2]);
        const float p3 = fast_exp2(s[mt][3]);
        sum += (p0 + p1) + (p2 + p3);
        pk[mt][0] = pack_bf2(p0, p1);
        pk[mt][1] = pack_bf2(p2, p3);
      }
      l_p[nt] += sum;
      // T12: in-register C-layout -> B-frag rearrangement (no LDS, no waits).
      unsigned int d0, d1, d2, d3, d4, d5, d6, d7;
      {
        i32x2 x, y;
        x = __builtin_amdgcn_permlane32_swap((int)pk[0][0], (int)pk[1][0], false, false);
        y = __builtin_amdgcn_permlane16_swap(x[0], x[1], false, false);
        d0 = (unsigned int)y[0]; d2 = (unsigned int)y[1];
        x = __builtin_amdgcn_permlane32_swap((int)pk[0][1], (int)pk[1][1], false, false);
        y = __builtin_amdgcn_permlane16_swap(x[0], x[1], false, false);
        d1 = (unsigned int)y[0]; d3 = (unsigned int)y[1];
        x = __builtin_amdgcn_permlane32_swap((int)pk[2][0], (int)pk[3][0], false, false);
        y = __builtin_amdgcn_permlane16_swap(x[0], x[1], false, false);
        d4 = (unsigned int)y[0]; d6 = (unsigned int)y[1];
        x = __builtin_amdgcn_permlane32_swap((int)pk[2][1], (int)pk[3][1], false, false);
        y = __builtin_amdgcn_permlane16_swap(x[0], x[1], false, false);
        d5 = (unsigned int)y[0]; d7 = (unsigned int)y[1];
      }
      const bf16x8 pb0 = __builtin_bit_cast(bf16x8, uint4{d0, d1, d2, d3});
      const bf16x8 pb1 = __builtin_bit_cast(bf16x8, uint4{d4, d5, d6, d7});
      __builtin_amdgcn_s_setprio(1);
#pragma unroll
      for (int mt = 0; mt < 4; ++mt) {
        o[mt][nt] = mfma16(vf0[mt], pb0, o[mt][nt]);  // O^T[d][qrow]
        o[mt][nt] = mfma16(vf1[mt], pb1, o[mt][nt]);
      }
      __builtin_amdgcn_s_setprio(0);
    }
  }

  // ---- merge (pure sums — fixed shift means no max weighting) ----
  __syncthreads();
  float* ob = obuf + w * 64 * 68;
#pragma unroll
  for (int nt = 0; nt < 4; ++nt) {
    ob[(16 * nt + c) * 68 + 64 + g] = l_p[nt];
#pragma unroll
    for (int mt = 0; mt < 4; ++mt)
      *reinterpret_cast<f32x4*>(&ob[(16 * nt + c) * 68 + 16 * mt + 4 * g]) = o[mt][nt];
  }
  __syncthreads();

  // wave w owns q-rows 16w..16w+15; lane (g,c) -> qrow 16w+c, dims 8g+j & 32+8g+j
  const int qr = 16 * w + c;
  float l = 0.f;
#pragma unroll
  for (int u = 0; u < 4; ++u)
#pragma unroll
    for (int gg = 0; gg < 4; ++gg) l += obuf[(u * 64 + qr) * 68 + 64 + gg];
  const float inv = 1.f / l;

  float acc[16];
#pragma unroll
  for (int j = 0; j < 16; ++j) acc[j] = 0.f;
#pragma unroll
  for (int u = 0; u < 4; ++u) {
    const float* src = obuf + (u * 64 + qr) * 68;
    f32x4 r0 = *reinterpret_cast<const f32x4*>(&src[8 * g]);
    f32x4 r1 = *reinterpret_cast<const f32x4*>(&src[8 * g + 4]);
    f32x4 r2 = *reinterpret_cast<const f32x4*>(&src[32 + 8 * g]);
    f32x4 r3 = *reinterpret_cast<const f32x4*>(&src[32 + 8 * g + 4]);
#pragma unroll
    for (int j = 0; j < 4; ++j) {
      acc[j] += r0[j];
      acc[4 + j] += r1[j];
      acc[8 + j] += r2[j];
      acc[12 + j] += r3[j];
    }
  }
  unsigned int od[8];
#pragma unroll
  for (int t = 0; t < 8; ++t) od[t] = pack_bf2(acc[2 * t] * inv, acc[2 * t + 1] * inv);
  unsigned short* orow = attn + ((long)(b * NN + q0 + qr)) * MODEL + h * 64;
  *reinterpret_cast<uint4*>(orow + 8 * g) = uint4{od[0], od[1], od[2], od[3]};
  *reinterpret_cast<uint4*>(orow + 32 + 8 * g) = uint4{od[4], od[5], od[6], od[7]};
}

// out[i][j] = sum_k attn[i][k] * w[j][k] + b[j]; tile 128x64, BK=64,
// 8-chunk XOR swizzle. v2: double-buffered LDS + single barrier/tile
// (T3-minimum 2-phase): stage(t+1) issued BEFORE compute(t) so the
// global_load_lds of the next tile overlaps this tile's MFMAs.
__global__ void proj_gemm_kernel(const unsigned short* __restrict__ A,
                                 const unsigned short* __restrict__ Bw,
                                 const float* __restrict__ bias,
                                 float* __restrict__ out) {
  __shared__ __align__(16) unsigned short At[2][128 * 64];
  __shared__ __align__(16) unsigned short Bt[2][64 * 64];
  int bm0 = blockIdx.x * 128, bn0 = blockIdx.y * 64;
  int tid = threadIdx.x, w = tid >> 6, lane = tid & 63;
  int g = lane >> 4, c = lane & 15;
  int m0 = (w & 1) * 64, n0 = (w >> 1) * 32;

  f32x4 acc[4][2];
#pragma unroll
  for (int mi = 0; mi < 4; ++mi)
#pragma unroll
    for (int nj = 0; nj < 2; ++nj) acc[mi][nj] = f32x4{0.f, 0.f, 0.f, 0.f};

  int rloc = lane >> 3, p = lane & 7;

  auto stage = [&](int buf, int kt) {
#pragma unroll
    for (int t = 0; t < 4; ++t) {
      int row = w * 32 + t * 8 + rloc;
      async_copy16(&At[buf][(w * 32 + t * 8) * 64],
                   A + (long)(bm0 + row) * 1024 + kt * 64 + (p ^ rloc) * 8);
    }
#pragma unroll
    for (int t = 0; t < 2; ++t) {
      int row = w * 16 + t * 8 + rloc;
      async_copy16(&Bt[buf][(w * 16 + t * 8) * 64],
                   Bw + (long)(bn0 + row) * 1024 + kt * 64 + (p ^ rloc) * 8);
    }
  };

  int cur = 0;
  stage(0, 0);
  for (int kt = 0; kt < 16; ++kt) {
    __syncthreads();  // drains vmcnt(0): tile kt resident; prev reads done
    if (kt < 15) stage(cur ^ 1, kt + 1);

    bf16x8 af0[4], af1[4], bf0[2], bf1[2];
#pragma unroll
    for (int mi = 0; mi < 4; ++mi) {
      int row = m0 + 16 * mi + c, sw = row & 7;
      af0[mi] = *reinterpret_cast<const bf16x8*>(&At[cur][row * 64 + (g ^ sw) * 8]);
      af1[mi] = *reinterpret_cast<const bf16x8*>(&At[cur][row * 64 + ((4 + g) ^ sw) * 8]);
    }
#pragma unroll
    for (int nj = 0; nj < 2; ++nj) {
      int row = n0 + 16 * nj + c, sw = row & 7;
      bf0[nj] = *reinterpret_cast<const bf16x8*>(&Bt[cur][row * 64 + (g ^ sw) * 8]);
      bf1[nj] = *reinterpret_cast<const bf16x8*>(&Bt[cur][row * 64 + ((4 + g) ^ sw) * 8]);
    }
#pragma unroll
    for (int mi = 0; mi < 4; ++mi)
#pragma unroll
      for (int nj = 0; nj < 2; ++nj) {
        acc[mi][nj] = mfma16(af0[mi], bf0[nj], acc[mi][nj]);
        acc[mi][nj] = mfma16(af1[mi], bf1[nj], acc[mi][nj]);
      }
    cur ^= 1;
  }

#pragma unroll
  for (int mi = 0; mi < 4; ++mi)
#pragma unroll
    for (int nj = 0; nj < 2; ++nj)
#pragma unroll
      for (int r = 0; r < 4; ++r) {
        int row = bm0 + m0 + mi * 16 + 4 * g + r;
        int col = bn0 + n0 + nj * 16 + c;
        out[(long)row * 1024 + col] = acc[mi][nj][r] + bias[col];
      }
}

extern "C" void kernel_launch(void* const* d_in, const int* in_sizes, int n_in,
                              void* d_out, int out_size, void* d_ws, size_t ws_size,
                              hipStream_t stream) {
  const float* q = (const float*)d_in[0];
  const float* k = (const float*)d_in[1];
  const float* v = (const float*)d_in[2];
  const float* rel_emb = (const float*)d_in[3];
  const float* w_out = (const float*)d_in[4];
  const float* b_out = (const float*)d_in[5];
  float* out = (float*)d_out;

  char* ws = (char*)d_ws;
  unsigned short* kb   = (unsigned short*)(ws + (8u << 20));
  unsigned short* vt   = (unsigned short*)(ws + (16u << 20));
  unsigned short* attn = (unsigned short*)(ws + (24u << 20));
  unsigned short* wb   = (unsigned short*)(ws + (32u << 20));
  float* biasTab       = (float*)(ws + (34u << 20));

  hipLaunchKernelGGL(prep_kernel, dim3(6161), dim3(256), 0, stream,
                     k, w_out, v, rel_emb, kb, wb, vt, biasTab);
  hipLaunchKernelGGL(flash13, dim3(1024), dim3(256), 0, stream,
                     q, kb, vt, biasTab, attn);
  hipLaunchKernelGGL(proj_gemm_kernel, dim3(32, 16), dim3(256), 0, stream,
                     attn, wb, b_out, out);
}